// Round 1
// baseline (510.605 us; speedup 1.0000x reference)
//
#include <hip/hip_runtime.h>
#include <hip/hip_bf16.h>

typedef __attribute__((ext_vector_type(8))) short short8;
typedef __attribute__((ext_vector_type(4))) float f32x4;
typedef __attribute__((ext_vector_type(4))) unsigned short u16x4;

#define D_MODEL 1024
#define N_HEAD 16
#define HEAD_DIM 64
#define T_SEQ 2048
#define BATCH 2
#define M_TOK (BATCH * T_SEQ) /* 4096 */

__device__ __forceinline__ unsigned short f2bf(float f) {
    union { float f; unsigned u; } v; v.f = f;
    unsigned r = (v.u + 0x7fffu + ((v.u >> 16) & 1u)) >> 16;  // RNE
    return (unsigned short)r;
}

// ---------------- cast x (f32 -> bf16), vectorized ----------------
__global__ __launch_bounds__(256) void cast_x(const float* __restrict__ in,
                                              unsigned short* __restrict__ out, int n4) {
    int i = blockIdx.x * 256 + threadIdx.x;
    if (i < n4) {
        float4 v = ((const float4*)in)[i];
        u16x4 o;
        o.x = f2bf(v.x); o.y = f2bf(v.y); o.z = f2bf(v.z); o.w = f2bf(v.w);
        ((u16x4*)out)[i] = o;
    }
}

// ---------------- transpose + cast W [R][C] f32 -> Wt [C][R] bf16 ----------------
__global__ __launch_bounds__(256) void transpose_cast(const float* __restrict__ in,
                                                      unsigned short* __restrict__ outT,
                                                      int R, int C) {
    __shared__ float tile[32][33];
    const int r0 = blockIdx.x * 32, c0 = blockIdx.y * 32;
    const int tx = threadIdx.x & 31, ty = threadIdx.x >> 5;  // ty 0..7
    #pragma unroll
    for (int jj = 0; jj < 32; jj += 8)
        tile[ty + jj][tx] = in[(size_t)(r0 + ty + jj) * C + c0 + tx];
    __syncthreads();
    #pragma unroll
    for (int jj = 0; jj < 32; jj += 8)
        outT[(size_t)(c0 + ty + jj) * R + r0 + tx] = f2bf(tile[tx][ty + jj]);
}

// ---------------- bf16 MFMA GEMM: C[M,N] = A[M,K] * Bt[N,K]^T ----------------
// mode 1: scatter bf16 into QKV buffers [3][B,H,T,Dh] (out = Q base; K,V contiguous after)
// mode 2: f32 out[M,N] + bias[n]
__global__ __launch_bounds__(256) void gemm_bf16(
    const unsigned short* __restrict__ A,
    const unsigned short* __restrict__ Bt,
    void* __restrict__ outp,
    const float* __restrict__ bias,
    int M, int N, int K, int mode)
{
    const int bm = blockIdx.x, bn = blockIdx.y;
    const int tid = threadIdx.x;
    const int w = tid >> 6, l = tid & 63, lo = l & 15, hi = l >> 4;
    const int wm = w >> 1, wn = w & 1;
    const int m0 = bm * 64 + wm * 32;
    const int n0 = bn * 64 + wn * 32;

    f32x4 acc[2][2];
    #pragma unroll
    for (int i = 0; i < 2; ++i)
        #pragma unroll
        for (int j = 0; j < 2; ++j)
            acc[i][j] = (f32x4){0.f, 0.f, 0.f, 0.f};

    const unsigned short* A0 = A + (size_t)(m0 + lo) * K + 8 * hi;
    const unsigned short* A1 = A + (size_t)(m0 + 16 + lo) * K + 8 * hi;
    const unsigned short* B0 = Bt + (size_t)(n0 + lo) * K + 8 * hi;
    const unsigned short* B1 = Bt + (size_t)(n0 + 16 + lo) * K + 8 * hi;

    #pragma unroll 2
    for (int k0 = 0; k0 < K; k0 += 32) {
        short8 a0 = *(const short8*)(A0 + k0);
        short8 a1 = *(const short8*)(A1 + k0);
        short8 b0 = *(const short8*)(B0 + k0);
        short8 b1 = *(const short8*)(B1 + k0);
        acc[0][0] = __builtin_amdgcn_mfma_f32_16x16x32_bf16(a0, b0, acc[0][0], 0, 0, 0);
        acc[0][1] = __builtin_amdgcn_mfma_f32_16x16x32_bf16(a0, b1, acc[0][1], 0, 0, 0);
        acc[1][0] = __builtin_amdgcn_mfma_f32_16x16x32_bf16(a1, b0, acc[1][0], 0, 0, 0);
        acc[1][1] = __builtin_amdgcn_mfma_f32_16x16x32_bf16(a1, b1, acc[1][1], 0, 0, 0);
    }

    if (mode == 1) {
        unsigned short* out = (unsigned short*)outp;
        #pragma unroll
        for (int i = 0; i < 2; ++i)
            #pragma unroll
            for (int j = 0; j < 2; ++j)
                #pragma unroll
                for (int e = 0; e < 4; ++e) {
                    const int m = m0 + i * 16 + 4 * hi + e;
                    const int n = n0 + j * 16 + lo;
                    const int b = m >> 11, t = m & 2047;
                    const int qkv = n >> 10, h = (n >> 6) & 15, d = n & 63;
                    const size_t off = (size_t)qkv * ((size_t)M_TOK * D_MODEL)
                                     + (((size_t)((b << 4) + h) * T_SEQ + t) * HEAD_DIM) + d;
                    out[off] = f2bf(acc[i][j][e]);
                }
    } else {
        float* out = (float*)outp;
        #pragma unroll
        for (int i = 0; i < 2; ++i)
            #pragma unroll
            for (int j = 0; j < 2; ++j)
                #pragma unroll
                for (int e = 0; e < 4; ++e) {
                    const int m = m0 + i * 16 + 4 * hi + e;
                    const int n = n0 + j * 16 + lo;
                    out[(size_t)m * N + n] = acc[i][j][e] + bias[n];
                }
    }
}

// ---------------- causal flash attention, 1 wave per (bh, 16-row q-tile) ----------------
__global__ __launch_bounds__(64) void attn_fwd(
    const unsigned short* __restrict__ Q,
    const unsigned short* __restrict__ K,
    const unsigned short* __restrict__ V,
    unsigned short* __restrict__ ctx)
{
    const int qt = blockIdx.x;   // 0..T/16-1
    const int bh = blockIdx.y;   // 0..B*H-1
    const int b = bh >> 4, h = bh & 15;
    const int l = threadIdx.x, lo = l & 15, hi = l >> 4;
    const int q0 = qt * 16;

    const unsigned short* Qb = Q + (size_t)bh * T_SEQ * HEAD_DIM;
    const unsigned short* Kb = K + (size_t)bh * T_SEQ * HEAD_DIM;
    const unsigned short* Vb = V + (size_t)bh * T_SEQ * HEAD_DIM;

    __shared__ unsigned short lds_p[16 * 32];

    const short8 qf0 = *(const short8*)(Qb + (size_t)(q0 + lo) * 64 + 8 * hi);
    const short8 qf1 = *(const short8*)(Qb + (size_t)(q0 + lo) * 64 + 32 + 8 * hi);

    f32x4 acc[4];
    #pragma unroll
    for (int cb = 0; cb < 4; ++cb) acc[cb] = (f32x4){0.f, 0.f, 0.f, 0.f};
    float mrow[4] = {-1e30f, -1e30f, -1e30f, -1e30f};
    float lrow[4] = {0.f, 0.f, 0.f, 0.f};

    const int nkb = (q0 + 16 + 31) >> 5;
    for (int kb = 0; kb < nkb; ++kb) {
        const int kbase = kb * 32;
        f32x4 s0 = (f32x4){0.f, 0.f, 0.f, 0.f};
        f32x4 s1 = (f32x4){0.f, 0.f, 0.f, 0.f};
        {
            const unsigned short* Kr0 = Kb + (size_t)(kbase + lo) * 64 + 8 * hi;
            const unsigned short* Kr1 = Kb + (size_t)(kbase + 16 + lo) * 64 + 8 * hi;
            short8 k00 = *(const short8*)(Kr0);
            short8 k01 = *(const short8*)(Kr0 + 32);
            short8 k10 = *(const short8*)(Kr1);
            short8 k11 = *(const short8*)(Kr1 + 32);
            s0 = __builtin_amdgcn_mfma_f32_16x16x32_bf16(qf0, k00, s0, 0, 0, 0);
            s0 = __builtin_amdgcn_mfma_f32_16x16x32_bf16(qf1, k01, s0, 0, 0, 0);
            s1 = __builtin_amdgcn_mfma_f32_16x16x32_bf16(qf0, k10, s1, 0, 0, 0);
            s1 = __builtin_amdgcn_mfma_f32_16x16x32_bf16(qf1, k11, s1, 0, 0, 0);
        }
        float p0[4], p1[4];
        #pragma unroll
        for (int e = 0; e < 4; ++e) {
            const int row = q0 + 4 * hi + e;
            float v0 = s0[e] * 0.125f;
            float v1 = s1[e] * 0.125f;
            if (kbase + lo > row)      v0 = -1e30f;
            if (kbase + 16 + lo > row) v1 = -1e30f;
            float mx = fmaxf(v0, v1);
            mx = fmaxf(mx, __shfl_xor(mx, 1));
            mx = fmaxf(mx, __shfl_xor(mx, 2));
            mx = fmaxf(mx, __shfl_xor(mx, 4));
            mx = fmaxf(mx, __shfl_xor(mx, 8));
            const float mnew = fmaxf(mrow[e], mx);
            const float sc = __expf(mrow[e] - mnew);
            const float e0 = __expf(v0 - mnew);
            const float e1 = __expf(v1 - mnew);
            float rs = e0 + e1;
            rs += __shfl_xor(rs, 1);
            rs += __shfl_xor(rs, 2);
            rs += __shfl_xor(rs, 4);
            rs += __shfl_xor(rs, 8);
            lrow[e] = lrow[e] * sc + rs;
            mrow[e] = mnew;
            p0[e] = e0; p1[e] = e1;
            #pragma unroll
            for (int cb = 0; cb < 4; ++cb) acc[cb][e] *= sc;
        }
        // P -> LDS (C-layout write), then read back in A-fragment layout
        #pragma unroll
        for (int e = 0; e < 4; ++e) {
            lds_p[(4 * hi + e) * 32 + lo]      = f2bf(p0[e]);
            lds_p[(4 * hi + e) * 32 + 16 + lo] = f2bf(p1[e]);
        }
        __syncthreads();
        const short8 pa = *(const short8*)(lds_p + lo * 32 + 8 * hi);
        #pragma unroll
        for (int cb = 0; cb < 4; ++cb) {
            short8 vf;
            #pragma unroll
            for (int e = 0; e < 8; ++e)
                vf[e] = (short)Vb[(size_t)(kbase + 8 * hi + e) * 64 + cb * 16 + lo];
            acc[cb] = __builtin_amdgcn_mfma_f32_16x16x32_bf16(pa, vf, acc[cb], 0, 0, 0);
        }
        __syncthreads();
    }
    // epilogue: ctx[b, t, h*64 + d] bf16
    #pragma unroll
    for (int cb = 0; cb < 4; ++cb) {
        #pragma unroll
        for (int e = 0; e < 4; ++e) {
            const int row = q0 + 4 * hi + e;
            const float val = acc[cb][e] / lrow[e];
            ctx[((size_t)(b * T_SEQ + row) * D_MODEL) + h * 64 + cb * 16 + lo] = f2bf(val);
        }
    }
}

extern "C" void kernel_launch(void* const* d_in, const int* in_sizes, int n_in,
                              void* d_out, int out_size, void* d_ws, size_t ws_size,
                              hipStream_t stream)
{
    const float* x  = (const float*)d_in[0];
    const float* Wq = (const float*)d_in[1];
    const float* Wk = (const float*)d_in[2];
    const float* Wv = (const float*)d_in[3];
    const float* Wo = (const float*)d_in[4];
    const float* bo = (const float*)d_in[5];
    float* out = (float*)d_out;

    char* ws = (char*)d_ws;
    unsigned short* x_bf = (unsigned short*)(ws);                  // 8 MiB  [4096][1024]
    unsigned short* WqT  = (unsigned short*)(ws + (8u << 20));     // 2 MiB  [1024][1024]
    unsigned short* WkT  = (unsigned short*)(ws + (10u << 20));    // 2 MiB  (contiguous with WqT)
    unsigned short* WvT  = (unsigned short*)(ws + (12u << 20));    // 2 MiB
    unsigned short* WoT  = (unsigned short*)(ws + (14u << 20));    // 2 MiB
    unsigned short* Qh   = (unsigned short*)(ws + (16u << 20));    // 8 MiB  [B,H,T,Dh]
    unsigned short* Kh   = (unsigned short*)(ws + (24u << 20));    // 8 MiB  (contiguous with Qh)
    unsigned short* Vh   = (unsigned short*)(ws + (32u << 20));    // 8 MiB
    unsigned short* ctx  = (unsigned short*)(ws + (40u << 20));    // 8 MiB  [4096][1024]
    (void)in_sizes; (void)n_in; (void)out_size; (void)ws_size; (void)Kh; (void)Vh;

    // 1. casts
    cast_x<<<dim3((M_TOK * D_MODEL / 4 + 255) / 256), 256, 0, stream>>>(x, x_bf, M_TOK * D_MODEL / 4);
    dim3 tg(32, 32);
    transpose_cast<<<tg, 256, 0, stream>>>(Wq, WqT, 1024, 1024);
    transpose_cast<<<tg, 256, 0, stream>>>(Wk, WkT, 1024, 1024);
    transpose_cast<<<tg, 256, 0, stream>>>(Wv, WvT, 1024, 1024);
    transpose_cast<<<tg, 256, 0, stream>>>(Wo, WoT, 1024, 1024);

    // 2. fused QKV projection: [4096,1024] x [1024,3072] -> scatter into Qh/Kh/Vh
    gemm_bf16<<<dim3(M_TOK / 64, 3072 / 64), 256, 0, stream>>>(
        x_bf, WqT, Qh, nullptr, M_TOK, 3072, D_MODEL, 1);

    // 3. causal flash attention
    attn_fwd<<<dim3(T_SEQ / 16, BATCH * N_HEAD), 64, 0, stream>>>(Qh, Kh, Vh, ctx);

    // 4. output projection + bias (f32 out)
    gemm_bf16<<<dim3(M_TOK / 64, D_MODEL / 64), 256, 0, stream>>>(
        ctx, WoT, out, bo, M_TOK, D_MODEL, D_MODEL, 2);
}

// Round 3
// 343.013 us; speedup vs baseline: 1.4886x; 1.4886x over previous
//
#include <hip/hip_runtime.h>
#include <hip/hip_bf16.h>

typedef __attribute__((ext_vector_type(8))) short short8;
typedef __attribute__((ext_vector_type(4))) float f32x4;
typedef __attribute__((ext_vector_type(4))) unsigned short u16x4;

#define D_MODEL 1024
#define N_HEAD 16
#define HEAD_DIM 64
#define T_SEQ 2048
#define BATCH 2
#define M_TOK (BATCH * T_SEQ) /* 4096 */

__device__ __forceinline__ unsigned short f2bf(float f) {
    union { float f; unsigned u; } v; v.f = f;
    unsigned r = (v.u + 0x7fffu + ((v.u >> 16) & 1u)) >> 16;  // RNE
    return (unsigned short)r;
}

__device__ __forceinline__ void load16_lds(const unsigned short* g, unsigned short* l) {
    __builtin_amdgcn_global_load_lds(
        (const __attribute__((address_space(1))) unsigned int*)(g),
        (__attribute__((address_space(3))) unsigned int*)(l),
        16, 0, 0);
}

// ---------------- cast x (f32 -> bf16), vectorized ----------------
__global__ __launch_bounds__(256) void cast_x(const float* __restrict__ in,
                                              unsigned short* __restrict__ out, int n4) {
    int i = blockIdx.x * 256 + threadIdx.x;
    if (i < n4) {
        float4 v = ((const float4*)in)[i];
        u16x4 o;
        o.x = f2bf(v.x); o.y = f2bf(v.y); o.z = f2bf(v.z); o.w = f2bf(v.w);
        ((u16x4*)out)[i] = o;
    }
}

// ---------------- transpose + cast all 4 weights [1024][1024] f32 -> bf16 T ----------------
__global__ __launch_bounds__(256) void transpose_cast4(
    const float* __restrict__ w0, const float* __restrict__ w1,
    const float* __restrict__ w2, const float* __restrict__ w3,
    unsigned short* __restrict__ o0, unsigned short* __restrict__ o1,
    unsigned short* __restrict__ o2, unsigned short* __restrict__ o3)
{
    __shared__ float tile[32][33];
    const float* in; unsigned short* outT;
    switch (blockIdx.z) {
        case 0: in = w0; outT = o0; break;
        case 1: in = w1; outT = o1; break;
        case 2: in = w2; outT = o2; break;
        default: in = w3; outT = o3; break;
    }
    const int R = 1024, C = 1024;
    const int r0 = blockIdx.x * 32, c0 = blockIdx.y * 32;
    const int tx = threadIdx.x & 31, ty = threadIdx.x >> 5;  // ty 0..7
    #pragma unroll
    for (int jj = 0; jj < 32; jj += 8)
        tile[ty + jj][tx] = in[(size_t)(r0 + ty + jj) * C + c0 + tx];
    __syncthreads();
    #pragma unroll
    for (int jj = 0; jj < 32; jj += 8)
        outT[(size_t)(c0 + ty + jj) * R + r0 + tx] = f2bf(tile[tx][ty + jj]);
}

// ---------------- m97-structure GEMM: C[M,N] = A[M,K] * Bt[N,K]^T ----------------
// 128x128 tile, BK=32, 4 waves (2x2), global_load_lds staging.
// mode 1: scatter bf16 into QKV buffers [3][B,H,T,Dh]
// mode 2: f32 out[M,N] + bias[n]
#define BM 128
#define BN 128
#define BK 32
__global__ __launch_bounds__(256) void gemm_bf16(
    const unsigned short* __restrict__ A,
    const unsigned short* __restrict__ Bt,
    void* __restrict__ outp,
    const float* __restrict__ bias,
    int M, int N, int K, int mode)
{
    __shared__ unsigned short lds_a[BM * BK];  // 8 KiB
    __shared__ unsigned short lds_b[BN * BK];  // 8 KiB
    const int tid = threadIdx.x;
    const int w = tid >> 6, l = tid & 63, lo = l & 15, hi = l >> 4;
    const int wm = w >> 1, wn = w & 1;
    const size_t arow0 = (size_t)blockIdx.x * BM;
    const size_t brow0 = (size_t)blockIdx.y * BN;

    f32x4 acc[4][4];
    #pragma unroll
    for (int i = 0; i < 4; ++i)
        #pragma unroll
        for (int j = 0; j < 4; ++j)
            acc[i][j] = (f32x4){0.f, 0.f, 0.f, 0.f};

    // staging map: chunk ch = it*256 + tid; row = ch>>2, col8 = (ch&3)*8
    const int ch0 = tid, ch1 = 256 + tid;
    const int r0c = ch0 >> 2, c0c = (ch0 & 3) * 8;
    const int r1c = ch1 >> 2, c1c = (ch1 & 3) * 8;
    const unsigned short* Ab0 = A + (arow0 + r0c) * K + c0c;
    const unsigned short* Ab1 = A + (arow0 + r1c) * K + c1c;
    const unsigned short* Bb0 = Bt + (brow0 + r0c) * K + c0c;
    const unsigned short* Bb1 = Bt + (brow0 + r1c) * K + c1c;
    unsigned short* la0 = lds_a + (size_t)(0 * 256 + w * 64) * 8;  // wave-uniform dest
    unsigned short* la1 = lds_a + (size_t)(1 * 256 + w * 64) * 8;
    unsigned short* lb0 = lds_b + (size_t)(0 * 256 + w * 64) * 8;
    unsigned short* lb1 = lds_b + (size_t)(1 * 256 + w * 64) * 8;

    for (int k0 = 0; k0 < K; k0 += BK) {
        load16_lds(Ab0 + k0, la0);
        load16_lds(Ab1 + k0, la1);
        load16_lds(Bb0 + k0, lb0);
        load16_lds(Bb1 + k0, lb1);
        __syncthreads();
        short8 af[4], bf[4];
        #pragma unroll
        for (int i = 0; i < 4; ++i)
            af[i] = *(const short8*)(lds_a + (wm * 64 + i * 16 + lo) * BK + 8 * hi);
        #pragma unroll
        for (int j = 0; j < 4; ++j)
            bf[j] = *(const short8*)(lds_b + (wn * 64 + j * 16 + lo) * BK + 8 * hi);
        #pragma unroll
        for (int i = 0; i < 4; ++i)
            #pragma unroll
            for (int j = 0; j < 4; ++j)
                acc[i][j] = __builtin_amdgcn_mfma_f32_16x16x32_bf16(af[i], bf[j], acc[i][j], 0, 0, 0);
        __syncthreads();
    }

    const int m00 = (int)arow0 + wm * 64;
    const int n00 = (int)brow0 + wn * 64;
    if (mode == 1) {
        unsigned short* out = (unsigned short*)outp;
        #pragma unroll
        for (int i = 0; i < 4; ++i)
            #pragma unroll
            for (int j = 0; j < 4; ++j)
                #pragma unroll
                for (int e = 0; e < 4; ++e) {
                    const int m = m00 + i * 16 + 4 * hi + e;
                    const int n = n00 + j * 16 + lo;
                    const int b = m >> 11, t = m & 2047;
                    const int qkv = n >> 10, h = (n >> 6) & 15, d = n & 63;
                    const size_t off = (size_t)qkv * ((size_t)M_TOK * D_MODEL)
                                     + (((size_t)((b << 4) + h) * T_SEQ + t) * HEAD_DIM) + d;
                    out[off] = f2bf(acc[i][j][e]);
                }
    } else {
        float* out = (float*)outp;
        #pragma unroll
        for (int i = 0; i < 4; ++i)
            #pragma unroll
            for (int j = 0; j < 4; ++j)
                #pragma unroll
                for (int e = 0; e < 4; ++e) {
                    const int m = m00 + i * 16 + 4 * hi + e;
                    const int n = n00 + j * 16 + lo;
                    out[(size_t)m * N + n] = acc[i][j][e] + bias[n];
                }
    }
}

// ---------------- V transpose per head: [B,H,T,64] -> [B,H,64,T] ----------------
__global__ __launch_bounds__(256) void transpose_v(const unsigned short* __restrict__ in,
                                                   unsigned short* __restrict__ out) {
    __shared__ unsigned short tile[32][33];
    const int t0 = blockIdx.x * 32, d0 = blockIdx.y * 32, bh = blockIdx.z;
    const int tx = threadIdx.x & 31, ty = threadIdx.x >> 5;
    const unsigned short* ib = in + (size_t)bh * T_SEQ * HEAD_DIM;
    unsigned short* ob = out + (size_t)bh * HEAD_DIM * T_SEQ;
    #pragma unroll
    for (int jj = 0; jj < 32; jj += 8)
        tile[ty + jj][tx] = ib[(size_t)(t0 + ty + jj) * HEAD_DIM + d0 + tx];
    __syncthreads();
    #pragma unroll
    for (int jj = 0; jj < 32; jj += 8)
        ob[(size_t)(d0 + ty + jj) * T_SEQ + t0 + tx] = tile[tx][ty + jj];
}

// ---------------- causal flash attention, 1 wave per (bh, 32-row q-tile) ----------------
__global__ __launch_bounds__(64) void attn_fwd(
    const unsigned short* __restrict__ Q,
    const unsigned short* __restrict__ K,
    const unsigned short* __restrict__ Vt,   // [B,H,64,T]
    unsigned short* __restrict__ ctx)
{
    const int qb = blockIdx.x;   // 0..T/32-1
    const int bh = blockIdx.y;   // 0..B*H-1
    const int b = bh >> 4, h = bh & 15;
    const int l = threadIdx.x, lo = l & 15, hi = l >> 4;
    const int q0 = qb * 32;

    const unsigned short* Qb = Q + (size_t)bh * T_SEQ * HEAD_DIM;
    const unsigned short* Kb = K + (size_t)bh * T_SEQ * HEAD_DIM;
    const unsigned short* Vb = Vt + (size_t)bh * HEAD_DIM * T_SEQ;

    __shared__ unsigned short lds_p[32 * 32];

    short8 qf[2][2];
    #pragma unroll
    for (int qt = 0; qt < 2; ++qt) {
        qf[qt][0] = *(const short8*)(Qb + (size_t)(q0 + qt * 16 + lo) * 64 + 8 * hi);
        qf[qt][1] = *(const short8*)(Qb + (size_t)(q0 + qt * 16 + lo) * 64 + 32 + 8 * hi);
    }

    f32x4 acc[2][4];
    float mrow[2][4], lrow[2][4];
    #pragma unroll
    for (int qt = 0; qt < 2; ++qt) {
        #pragma unroll
        for (int cb = 0; cb < 4; ++cb) acc[qt][cb] = (f32x4){0.f, 0.f, 0.f, 0.f};
        #pragma unroll
        for (int e = 0; e < 4; ++e) { mrow[qt][e] = -1e30f; lrow[qt][e] = 0.f; }
    }

    const int nkb = q0 / 32 + 1;
    for (int kb = 0; kb < nkb; ++kb) {
        const int kbase = kb * 32;
        short8 kf[2][2];
        {
            const unsigned short* Kr0 = Kb + (size_t)(kbase + lo) * 64 + 8 * hi;
            const unsigned short* Kr1 = Kb + (size_t)(kbase + 16 + lo) * 64 + 8 * hi;
            kf[0][0] = *(const short8*)(Kr0);
            kf[0][1] = *(const short8*)(Kr0 + 32);
            kf[1][0] = *(const short8*)(Kr1);
            kf[1][1] = *(const short8*)(Kr1 + 32);
        }
        f32x4 s[2][2];
        #pragma unroll
        for (int qt = 0; qt < 2; ++qt)
            #pragma unroll
            for (int kr = 0; kr < 2; ++kr) {
                s[qt][kr] = (f32x4){0.f, 0.f, 0.f, 0.f};
                s[qt][kr] = __builtin_amdgcn_mfma_f32_16x16x32_bf16(qf[qt][0], kf[kr][0], s[qt][kr], 0, 0, 0);
                s[qt][kr] = __builtin_amdgcn_mfma_f32_16x16x32_bf16(qf[qt][1], kf[kr][1], s[qt][kr], 0, 0, 0);
            }
        #pragma unroll
        for (int qt = 0; qt < 2; ++qt) {
            #pragma unroll
            for (int e = 0; e < 4; ++e) {
                const int row = q0 + qt * 16 + 4 * hi + e;
                float v0 = s[qt][0][e] * 0.125f;
                float v1 = s[qt][1][e] * 0.125f;
                if (kbase + lo > row)      v0 = -1e30f;
                if (kbase + 16 + lo > row) v1 = -1e30f;
                float mx = fmaxf(v0, v1);
                mx = fmaxf(mx, __shfl_xor(mx, 1));
                mx = fmaxf(mx, __shfl_xor(mx, 2));
                mx = fmaxf(mx, __shfl_xor(mx, 4));
                mx = fmaxf(mx, __shfl_xor(mx, 8));
                const float mnew = fmaxf(mrow[qt][e], mx);
                const float sc = __expf(mrow[qt][e] - mnew);
                const float e0 = __expf(v0 - mnew);
                const float e1 = __expf(v1 - mnew);
                float rs = e0 + e1;
                rs += __shfl_xor(rs, 1);
                rs += __shfl_xor(rs, 2);
                rs += __shfl_xor(rs, 4);
                rs += __shfl_xor(rs, 8);
                lrow[qt][e] = lrow[qt][e] * sc + rs;
                mrow[qt][e] = mnew;
                lds_p[(qt * 16 + 4 * hi + e) * 32 + lo]      = f2bf(e0);
                lds_p[(qt * 16 + 4 * hi + e) * 32 + 16 + lo] = f2bf(e1);
                #pragma unroll
                for (int cb = 0; cb < 4; ++cb) acc[qt][cb][e] *= sc;
            }
        }
        __syncthreads();
        short8 pa[2];
        pa[0] = *(const short8*)(lds_p + (size_t)lo * 32 + 8 * hi);
        pa[1] = *(const short8*)(lds_p + (size_t)(16 + lo) * 32 + 8 * hi);
        short8 vf[4];
        #pragma unroll
        for (int cb = 0; cb < 4; ++cb)
            vf[cb] = *(const short8*)(Vb + (size_t)(cb * 16 + lo) * T_SEQ + kbase + 8 * hi);
        #pragma unroll
        for (int qt = 0; qt < 2; ++qt)
            #pragma unroll
            for (int cb = 0; cb < 4; ++cb)
                acc[qt][cb] = __builtin_amdgcn_mfma_f32_16x16x32_bf16(pa[qt], vf[cb], acc[qt][cb], 0, 0, 0);
        __syncthreads();
    }
    #pragma unroll
    for (int qt = 0; qt < 2; ++qt)
        #pragma unroll
        for (int cb = 0; cb < 4; ++cb)
            #pragma unroll
            for (int e = 0; e < 4; ++e) {
                const int row = q0 + qt * 16 + 4 * hi + e;
                const float val = acc[qt][cb][e] / lrow[qt][e];
                ctx[((size_t)(b * T_SEQ + row) * D_MODEL) + h * 64 + cb * 16 + lo] = f2bf(val);
            }
}

extern "C" void kernel_launch(void* const* d_in, const int* in_sizes, int n_in,
                              void* d_out, int out_size, void* d_ws, size_t ws_size,
                              hipStream_t stream)
{
    const float* x  = (const float*)d_in[0];
    const float* Wq = (const float*)d_in[1];
    const float* Wk = (const float*)d_in[2];
    const float* Wv = (const float*)d_in[3];
    const float* Wo = (const float*)d_in[4];
    const float* bo = (const float*)d_in[5];
    float* out = (float*)d_out;

    char* ws = (char*)d_ws;
    unsigned short* x_bf = (unsigned short*)(ws);                  // 8 MiB [4096][1024]; reused as Vt later
    unsigned short* WqT  = (unsigned short*)(ws + (8u << 20));     // 2 MiB
    unsigned short* WkT  = (unsigned short*)(ws + (10u << 20));    // 2 MiB
    unsigned short* WvT  = (unsigned short*)(ws + (12u << 20));    // 2 MiB
    unsigned short* WoT  = (unsigned short*)(ws + (14u << 20));    // 2 MiB
    unsigned short* Qh   = (unsigned short*)(ws + (16u << 20));    // 8 MiB [B,H,T,Dh]
    unsigned short* Vraw = (unsigned short*)(ws + (32u << 20));    // 8 MiB (QKV scatter target for V)
    unsigned short* Vt   = (unsigned short*)(ws);                  // 8 MiB [B,H,Dh,T] (aliases x_bf)
    unsigned short* Kh   = (unsigned short*)(ws + (24u << 20));    // (implicit: Qh+M*D)
    unsigned short* ctx  = (unsigned short*)(ws + (40u << 20));    // 8 MiB [4096][1024]
    (void)in_sizes; (void)n_in; (void)out_size; (void)ws_size; (void)Kh;

    // 1. casts
    cast_x<<<dim3((M_TOK * D_MODEL / 4 + 255) / 256), 256, 0, stream>>>(x, x_bf, M_TOK * D_MODEL / 4);
    transpose_cast4<<<dim3(32, 32, 4), 256, 0, stream>>>(Wq, Wk, Wv, Wo, WqT, WkT, WvT, WoT);

    // 2. fused QKV projection: [4096,1024] x [1024,3072] -> scatter Q,K,V
    gemm_bf16<<<dim3(M_TOK / BM, 3072 / BN), 256, 0, stream>>>(
        x_bf, WqT, Qh, nullptr, M_TOK, 3072, D_MODEL, 1);

    // 3. V transpose (x_bf is dead now; Vt aliases it)
    transpose_v<<<dim3(T_SEQ / 32, HEAD_DIM / 32, BATCH * N_HEAD), 256, 0, stream>>>(Vraw, Vt);

    // 4. causal flash attention (32 q-rows per wave)
    attn_fwd<<<dim3(T_SEQ / 32, BATCH * N_HEAD), 64, 0, stream>>>(Qh, Kh, Vt, ctx);

    // 5. output projection + bias (f32 out)
    gemm_bf16<<<dim3(M_TOK / BM, D_MODEL / BN), 256, 0, stream>>>(
        ctx, WoT, out, bo, M_TOK, D_MODEL, D_MODEL, 2);
}

// Round 4
// 272.336 us; speedup vs baseline: 1.8749x; 1.2595x over previous
//
#include <hip/hip_runtime.h>
#include <hip/hip_bf16.h>

typedef __attribute__((ext_vector_type(8))) short short8;
typedef __attribute__((ext_vector_type(4))) float f32x4;
typedef __attribute__((ext_vector_type(4))) unsigned short u16x4;

#define D_MODEL 1024
#define N_HEAD 16
#define HEAD_DIM 64
#define T_SEQ 2048
#define BATCH 2
#define M_TOK (BATCH * T_SEQ) /* 4096 */
#define QKV_STRIDE ((size_t)M_TOK * D_MODEL) /* elems per Q/K/V buffer */

__device__ __forceinline__ unsigned short f2bf(float f) {
    union { float f; unsigned u; } v; v.f = f;
    unsigned r = (v.u + 0x7fffu + ((v.u >> 16) & 1u)) >> 16;  // RNE
    return (unsigned short)r;
}

__device__ __forceinline__ void load16_lds(const unsigned short* g, unsigned short* l) {
    __builtin_amdgcn_global_load_lds(
        (const __attribute__((address_space(1))) unsigned int*)(g),
        (__attribute__((address_space(3))) unsigned int*)(l),
        16, 0, 0);
}

// ---------------- cast x (f32 -> bf16), vectorized ----------------
__global__ __launch_bounds__(256) void cast_x(const float* __restrict__ in,
                                              unsigned short* __restrict__ out, int n4) {
    int i = blockIdx.x * 256 + threadIdx.x;
    if (i < n4) {
        float4 v = ((const float4*)in)[i];
        u16x4 o;
        o.x = f2bf(v.x); o.y = f2bf(v.y); o.z = f2bf(v.z); o.w = f2bf(v.w);
        ((u16x4*)out)[i] = o;
    }
}

// ---------------- transpose + cast all 4 weights [1024][1024] f32 -> bf16 T ----------------
__global__ __launch_bounds__(256) void transpose_cast4(
    const float* __restrict__ w0, const float* __restrict__ w1,
    const float* __restrict__ w2, const float* __restrict__ w3,
    unsigned short* __restrict__ o0, unsigned short* __restrict__ o1,
    unsigned short* __restrict__ o2, unsigned short* __restrict__ o3)
{
    __shared__ float tile[32][33];
    const float* in; unsigned short* outT;
    switch (blockIdx.z) {
        case 0: in = w0; outT = o0; break;
        case 1: in = w1; outT = o1; break;
        case 2: in = w2; outT = o2; break;
        default: in = w3; outT = o3; break;
    }
    const int R = 1024, C = 1024;
    const int r0 = blockIdx.x * 32, c0 = blockIdx.y * 32;
    const int tx = threadIdx.x & 31, ty = threadIdx.x >> 5;  // ty 0..7
    #pragma unroll
    for (int jj = 0; jj < 32; jj += 8)
        tile[ty + jj][tx] = in[(size_t)(r0 + ty + jj) * C + c0 + tx];
    __syncthreads();
    #pragma unroll
    for (int jj = 0; jj < 32; jj += 8)
        outT[(size_t)(c0 + ty + jj) * R + r0 + tx] = f2bf(tile[tx][ty + jj]);
}

// ---------------- m97-structure GEMM: C[M,N] = A[M,K] * Bt[N,K]^T ----------------
// mode 1: scatter into QKV buffers: Q raw [B,H,T,Dh]; K scaled by 0.125 [B,H,T,Dh];
//         V transposed [B,H,Dh,T]. outp = base of Q; K at +QKV_STRIDE, V at +2*QKV_STRIDE.
// mode 2: f32 out[M,N] + bias[n]
#define BM 128
#define BN 128
#define BK 32
__global__ __launch_bounds__(256) void gemm_bf16(
    const unsigned short* __restrict__ A,
    const unsigned short* __restrict__ Bt,
    void* __restrict__ outp,
    const float* __restrict__ bias,
    int M, int N, int K, int mode)
{
    __shared__ unsigned short lds_a[BM * BK];  // 8 KiB
    __shared__ unsigned short lds_b[BN * BK];  // 8 KiB
    const int tid = threadIdx.x;
    const int w = tid >> 6, l = tid & 63, lo = l & 15, hi = l >> 4;
    const int wm = w >> 1, wn = w & 1;
    const size_t arow0 = (size_t)blockIdx.x * BM;
    const size_t brow0 = (size_t)blockIdx.y * BN;

    f32x4 acc[4][4];
    #pragma unroll
    for (int i = 0; i < 4; ++i)
        #pragma unroll
        for (int j = 0; j < 4; ++j)
            acc[i][j] = (f32x4){0.f, 0.f, 0.f, 0.f};

    const int ch0 = tid, ch1 = 256 + tid;
    const int r0c = ch0 >> 2, c0c = (ch0 & 3) * 8;
    const int r1c = ch1 >> 2, c1c = (ch1 & 3) * 8;
    const unsigned short* Ab0 = A + (arow0 + r0c) * K + c0c;
    const unsigned short* Ab1 = A + (arow0 + r1c) * K + c1c;
    const unsigned short* Bb0 = Bt + (brow0 + r0c) * K + c0c;
    const unsigned short* Bb1 = Bt + (brow0 + r1c) * K + c1c;
    unsigned short* la0 = lds_a + (size_t)(0 * 256 + w * 64) * 8;
    unsigned short* la1 = lds_a + (size_t)(1 * 256 + w * 64) * 8;
    unsigned short* lb0 = lds_b + (size_t)(0 * 256 + w * 64) * 8;
    unsigned short* lb1 = lds_b + (size_t)(1 * 256 + w * 64) * 8;

    for (int k0 = 0; k0 < K; k0 += BK) {
        load16_lds(Ab0 + k0, la0);
        load16_lds(Ab1 + k0, la1);
        load16_lds(Bb0 + k0, lb0);
        load16_lds(Bb1 + k0, lb1);
        __syncthreads();
        short8 af[4], bfr[4];
        #pragma unroll
        for (int i = 0; i < 4; ++i)
            af[i] = *(const short8*)(lds_a + (wm * 64 + i * 16 + lo) * BK + 8 * hi);
        #pragma unroll
        for (int j = 0; j < 4; ++j)
            bfr[j] = *(const short8*)(lds_b + (wn * 64 + j * 16 + lo) * BK + 8 * hi);
        #pragma unroll
        for (int i = 0; i < 4; ++i)
            #pragma unroll
            for (int j = 0; j < 4; ++j)
                acc[i][j] = __builtin_amdgcn_mfma_f32_16x16x32_bf16(af[i], bfr[j], acc[i][j], 0, 0, 0);
        __syncthreads();
    }

    const int m00 = (int)arow0 + wm * 64;
    const int n00 = (int)brow0 + wn * 64;
    if (mode == 1) {
        unsigned short* out = (unsigned short*)outp;
        #pragma unroll
        for (int i = 0; i < 4; ++i)
            #pragma unroll
            for (int j = 0; j < 4; ++j) {
                const int nbase = n00 + j * 16;
                const int qkv = nbase >> 10;          // block-uniform
                #pragma unroll
                for (int e = 0; e < 4; ++e) {
                    const int m = m00 + i * 16 + 4 * hi + e;
                    const int n = nbase + lo;
                    const int b = m >> 11, t = m & 2047;
                    const int h = (n >> 6) & 15, d = n & 63;
                    const int bh = (b << 4) + h;
                    float v = acc[i][j][e];
                    size_t off;
                    if (qkv == 0) {
                        off = ((size_t)bh * T_SEQ + t) * HEAD_DIM + d;
                    } else if (qkv == 1) {
                        v *= 0.125f;  // fold 1/sqrt(Dh) into K
                        off = QKV_STRIDE + ((size_t)bh * T_SEQ + t) * HEAD_DIM + d;
                    } else {
                        off = 2 * QKV_STRIDE + ((size_t)bh * HEAD_DIM + d) * T_SEQ + t;  // V^T
                    }
                    out[off] = f2bf(v);
                }
            }
    } else {
        float* out = (float*)outp;
        #pragma unroll
        for (int i = 0; i < 4; ++i)
            #pragma unroll
            for (int j = 0; j < 4; ++j)
                #pragma unroll
                for (int e = 0; e < 4; ++e) {
                    const int m = m00 + i * 16 + 4 * hi + e;
                    const int n = n00 + j * 16 + lo;
                    out[(size_t)m * N + n] = acc[i][j][e] + bias[n];
                }
    }
}

// ---------------- causal flash attention, swapped QK^T, in-register softmax ----------------
// 1 wave per (bh, 32-row q-tile). S^T = mfma(K, Q): lane owns q-row = lane&15 per qt-half.
__global__ __launch_bounds__(64) void attn_fwd(
    const unsigned short* __restrict__ QKV,   // Q | K(pre-scaled) | V^T
    unsigned short* __restrict__ ctx)
{
    const int qb = (int)(gridDim.x - 1 - blockIdx.x);  // longest-first
    const int bh = blockIdx.y;
    const int b = bh >> 4, h = bh & 15;
    const int l = threadIdx.x, lo = l & 15, hi = l >> 4;
    const int q0 = qb * 32;

    const unsigned short* Qb = QKV + (size_t)bh * T_SEQ * HEAD_DIM;
    const unsigned short* Kb = QKV + QKV_STRIDE + (size_t)bh * T_SEQ * HEAD_DIM;
    const unsigned short* Vb = QKV + 2 * QKV_STRIDE + (size_t)bh * HEAD_DIM * T_SEQ;

    __shared__ unsigned short lds_p[32 * 32];  // [q_local][k_local], 64B rows

    short8 qf[2][2];
    #pragma unroll
    for (int qt = 0; qt < 2; ++qt) {
        qf[qt][0] = *(const short8*)(Qb + (size_t)(q0 + qt * 16 + lo) * 64 + 8 * hi);
        qf[qt][1] = *(const short8*)(Qb + (size_t)(q0 + qt * 16 + lo) * 64 + 32 + 8 * hi);
    }

    f32x4 acc[2][4];
    float mrow[2] = {-3e38f, -3e38f}, lrow[2] = {0.f, 0.f};
    #pragma unroll
    for (int qt = 0; qt < 2; ++qt)
        #pragma unroll
        for (int cb = 0; cb < 4; ++cb) acc[qt][cb] = (f32x4){0.f, 0.f, 0.f, 0.f};

    const int nkb = qb + 1;
    for (int kb = 0; kb < nkb; ++kb) {
        const int kbase = kb * 32;
        short8 kf[2][2];
        {
            const unsigned short* Kr0 = Kb + (size_t)(kbase + lo) * 64 + 8 * hi;
            const unsigned short* Kr1 = Kb + (size_t)(kbase + 16 + lo) * 64 + 8 * hi;
            kf[0][0] = *(const short8*)(Kr0);
            kf[0][1] = *(const short8*)(Kr0 + 32);
            kf[1][0] = *(const short8*)(Kr1);
            kf[1][1] = *(const short8*)(Kr1 + 32);
        }
        // S^T tiles: s[kr][qt]; element (k = kbase+kr*16+4*hi+e, q = q0+qt*16+lo)
        f32x4 s[2][2];
        #pragma unroll
        for (int kr = 0; kr < 2; ++kr)
            #pragma unroll
            for (int qt = 0; qt < 2; ++qt) {
                s[kr][qt] = (f32x4){0.f, 0.f, 0.f, 0.f};
                s[kr][qt] = __builtin_amdgcn_mfma_f32_16x16x32_bf16(kf[kr][0], qf[qt][0], s[kr][qt], 0, 0, 0);
                s[kr][qt] = __builtin_amdgcn_mfma_f32_16x16x32_bf16(kf[kr][1], qf[qt][1], s[kr][qt], 0, 0, 0);
            }
        if (kb == nkb - 1) {  // only the last k-block straddles the diagonal
            #pragma unroll
            for (int kr = 0; kr < 2; ++kr)
                #pragma unroll
                for (int qt = 0; qt < 2; ++qt)
                    #pragma unroll
                    for (int e = 0; e < 4; ++e)
                        if (kr * 16 + 4 * hi + e > qt * 16 + lo) s[kr][qt][e] = -3e38f;
        }
        #pragma unroll
        for (int qt = 0; qt < 2; ++qt) {
            float pm = fmaxf(fmaxf(fmaxf(s[0][qt][0], s[0][qt][1]), fmaxf(s[0][qt][2], s[0][qt][3])),
                             fmaxf(fmaxf(s[1][qt][0], s[1][qt][1]), fmaxf(s[1][qt][2], s[1][qt][3])));
            pm = fmaxf(pm, __shfl_xor(pm, 16));
            pm = fmaxf(pm, __shfl_xor(pm, 32));
            const int need = pm > mrow[qt] + 8.0f;   // defer-max (T13)
            if (__any(need)) {
                const float mnew = fmaxf(mrow[qt], pm);
                const float sc = __expf(mrow[qt] - mnew);
                mrow[qt] = mnew;
                lrow[qt] *= sc;
                #pragma unroll
                for (int cb = 0; cb < 4; ++cb)
                    #pragma unroll
                    for (int e = 0; e < 4; ++e) acc[qt][cb][e] *= sc;
            }
            float p[8];
            #pragma unroll
            for (int kr = 0; kr < 2; ++kr)
                #pragma unroll
                for (int e = 0; e < 4; ++e)
                    p[kr * 4 + e] = __expf(s[kr][qt][e] - mrow[qt]);
            float rs = ((p[0] + p[1]) + (p[2] + p[3])) + ((p[4] + p[5]) + (p[6] + p[7]));
            rs += __shfl_xor(rs, 16);
            rs += __shfl_xor(rs, 32);
            lrow[qt] += rs;
            unsigned r0, r1, r2, r3;
            asm volatile("v_cvt_pk_bf16_f32 %0, %1, %2" : "=v"(r0) : "v"(p[0]), "v"(p[1]));
            asm volatile("v_cvt_pk_bf16_f32 %0, %1, %2" : "=v"(r1) : "v"(p[2]), "v"(p[3]));
            asm volatile("v_cvt_pk_bf16_f32 %0, %1, %2" : "=v"(r2) : "v"(p[4]), "v"(p[5]));
            asm volatile("v_cvt_pk_bf16_f32 %0, %1, %2" : "=v"(r3) : "v"(p[6]), "v"(p[7]));
            char* rowp = (char*)lds_p + (qt * 16 + lo) * 64;
            *(uint2*)(rowp + 8 * hi)      = (uint2){r0, r1};   // kr=0: k_local 4hi..4hi+3
            *(uint2*)(rowp + 32 + 8 * hi) = (uint2){r2, r3};   // kr=1
        }
        __syncthreads();
        short8 pa[2];
        pa[0] = *(const short8*)((char*)lds_p + (size_t)lo * 64 + 16 * hi);
        pa[1] = *(const short8*)((char*)lds_p + (size_t)(16 + lo) * 64 + 16 * hi);
        short8 vf[4];
        #pragma unroll
        for (int cb = 0; cb < 4; ++cb)
            vf[cb] = *(const short8*)(Vb + (size_t)(cb * 16 + lo) * T_SEQ + kbase + 8 * hi);
        #pragma unroll
        for (int qt = 0; qt < 2; ++qt)
            #pragma unroll
            for (int cb = 0; cb < 4; ++cb)
                acc[qt][cb] = __builtin_amdgcn_mfma_f32_16x16x32_bf16(pa[qt], vf[cb], acc[qt][cb], 0, 0, 0);
        __syncthreads();
    }
    // epilogue: lane (hi,e) row = 4hi+e needs lrow held in lane lo'=4hi+e
    #pragma unroll
    for (int qt = 0; qt < 2; ++qt) {
        #pragma unroll
        for (int e = 0; e < 4; ++e) {
            const float lr = __shfl(lrow[qt], 4 * hi + e);
            const float inv = 1.0f / lr;
            const int row = q0 + qt * 16 + 4 * hi + e;
            #pragma unroll
            for (int cb = 0; cb < 4; ++cb)
                ctx[((size_t)(b * T_SEQ + row) * D_MODEL) + h * 64 + cb * 16 + lo] =
                    f2bf(acc[qt][cb][e] * inv);
        }
    }
}

extern "C" void kernel_launch(void* const* d_in, const int* in_sizes, int n_in,
                              void* d_out, int out_size, void* d_ws, size_t ws_size,
                              hipStream_t stream)
{
    const float* x  = (const float*)d_in[0];
    const float* Wq = (const float*)d_in[1];
    const float* Wk = (const float*)d_in[2];
    const float* Wv = (const float*)d_in[3];
    const float* Wo = (const float*)d_in[4];
    const float* bo = (const float*)d_in[5];
    float* out = (float*)d_out;

    char* ws = (char*)d_ws;
    unsigned short* x_bf = (unsigned short*)(ws);                  // 8 MiB [4096][1024]
    unsigned short* WqT  = (unsigned short*)(ws + (8u << 20));     // 2 MiB
    unsigned short* WkT  = (unsigned short*)(ws + (10u << 20));    // 2 MiB
    unsigned short* WvT  = (unsigned short*)(ws + (12u << 20));    // 2 MiB
    unsigned short* WoT  = (unsigned short*)(ws + (14u << 20));    // 2 MiB
    unsigned short* QKV  = (unsigned short*)(ws + (16u << 20));    // 24 MiB: Q | K*0.125 | V^T
    unsigned short* ctx  = (unsigned short*)(ws + (40u << 20));    // 8 MiB [4096][1024]
    (void)in_sizes; (void)n_in; (void)out_size; (void)ws_size;

    cast_x<<<dim3((M_TOK * D_MODEL / 4 + 255) / 256), 256, 0, stream>>>(x, x_bf, M_TOK * D_MODEL / 4);
    transpose_cast4<<<dim3(32, 32, 4), 256, 0, stream>>>(Wq, Wk, Wv, Wo, WqT, WkT, WvT, WoT);

    gemm_bf16<<<dim3(M_TOK / BM, 3072 / BN), 256, 0, stream>>>(
        x_bf, WqT, QKV, nullptr, M_TOK, 3072, D_MODEL, 1);

    attn_fwd<<<dim3(T_SEQ / 32, BATCH * N_HEAD), 64, 0, stream>>>(QKV, ctx);

    gemm_bf16<<<dim3(M_TOK / BM, D_MODEL / BN), 256, 0, stream>>>(
        ctx, WoT, out, bo, M_TOK, D_MODEL, D_MODEL, 2);
}